// Round 5
// baseline (128.375 us; speedup 1.0000x reference)
//
#include <hip/hip_runtime.h>
#include <hip/hip_bf16.h>
#include <stdint.h>

// out_re[b,i] = sum_j T_re[j,i]*p[i,j] - T_im[j,i]*q[i,j]   (d_out = Re only)
//   T_re = R*P^T + M*Q^T ; T_im = M*P^T - R*Q^T  via 16x16x32 bf16 MFMA.
// Round-5 restructure: NB=4 batches per block (grid=B/4), K staged in LDS once,
// rolling register prefetch of X (next kT / next batch issued before use),
// Re-only epilogue with coalesced f32x4 k-weight loads, partials in a separate
// 4KB dynamic-LDS region (total 68KB dynamic, set via hipFuncSetAttribute).

typedef __attribute__((ext_vector_type(8))) __bf16 bf16x8;
typedef __attribute__((ext_vector_type(4))) float f32x4;
typedef __attribute__((ext_vector_type(4))) unsigned int u32x4;

#define EDIM 128
#define NB 4
#define LDS_BYTES (65536 + 4096)

static __device__ inline bf16x8 neg8(bf16x8 v) {
    u32x4 u = __builtin_bit_cast(u32x4, v);
    u ^= (u32x4){0x80008000u, 0x80008000u, 0x80008000u, 0x80008000u};
    return __builtin_bit_cast(bf16x8, u);
}

__global__ __launch_bounds__(512, 4) void qmeas_kernel(
    const float* __restrict__ R, const float* __restrict__ M,
    const float* __restrict__ Kern, float* __restrict__ out,
    int B, int nout)
{
    extern __shared__ unsigned char smem[];          // [0,32K) Pb, [32K,64K) Qb, [64K,68K) part
    float* part = (float*)(smem + 65536);            // f32 part[8][128] (Re only)

    const int t    = threadIdx.x;
    const int lane = t & 63;
    const int w    = t >> 6;       // wave 0..7
    const int li   = lane & 15;
    const int s    = lane >> 4;    // 0..3
    const int b0   = blockIdx.x * NB;

    // ---- stage kernel (f32 interleaved p,q -> bf16 Pb/Qb, XOR-swizzled) ----
    for (int it = 0; it < 4; ++it) {
        int idx = t + it * 512;            // 0..2047
        int i   = idx >> 4;                // row 0..127
        int l0  = (idx & 15) << 3;         // 0,8,...,120
        const float* g = Kern + (((size_t)i * EDIM + l0) << 1);
        f32x4 f0 = *(const f32x4*)(g);
        f32x4 f1 = *(const f32x4*)(g + 4);
        f32x4 f2 = *(const f32x4*)(g + 8);
        f32x4 f3 = *(const f32x4*)(g + 12);
        bf16x8 pv, qv;
        pv[0] = (__bf16)f0[0]; qv[0] = (__bf16)f0[1];
        pv[1] = (__bf16)f0[2]; qv[1] = (__bf16)f0[3];
        pv[2] = (__bf16)f1[0]; qv[2] = (__bf16)f1[1];
        pv[3] = (__bf16)f1[2]; qv[3] = (__bf16)f1[3];
        pv[4] = (__bf16)f2[0]; qv[4] = (__bf16)f2[1];
        pv[5] = (__bf16)f2[2]; qv[5] = (__bf16)f2[3];
        pv[6] = (__bf16)f3[0]; qv[6] = (__bf16)f3[1];
        pv[7] = (__bf16)f3[2]; qv[7] = (__bf16)f3[3];
        int off = (i * 256 + (l0 << 1)) ^ ((i & 7) << 4);
        *(bf16x8*)(smem + off)         = pv;   // Pb
        *(bf16x8*)(smem + 32768 + off) = qv;   // Qb
    }
    __syncthreads();

    const int    jj   = (w << 4) + li;            // this lane's A-row (j)
    const size_t xrow = (size_t)b0 * (EDIM * EDIM) + (size_t)jj * EDIM + (size_t)(s * 8);
    const float* Rp = R + xrow;
    const float* Mp = M + xrow;

    // rolling X prefetch registers
    f32x4 cr0 = *(const f32x4*)(Rp);
    f32x4 cr1 = *(const f32x4*)(Rp + 4);
    f32x4 cm0 = *(const f32x4*)(Mp);
    f32x4 cm1 = *(const f32x4*)(Mp + 4);

    for (int bb = 0; bb < NB; ++bb) {
        const int b = b0 + bb;
        if (b >= B) break;

        f32x4 acc_re[8], acc_im[8];
#pragma unroll
        for (int n = 0; n < 8; ++n) {
            acc_re[n] = (f32x4){0.f, 0.f, 0.f, 0.f};
            acc_im[n] = (f32x4){0.f, 0.f, 0.f, 0.f};
        }

#pragma unroll
        for (int kT = 0; kT < 4; ++kT) {
            // ---- prefetch next kT (or next batch's kT=0) ----
            f32x4 nr0, nr1, nm0, nm1;
            const bool dopf = (kT < 3) || (bb + 1 < NB && b + 1 < B);
            if (dopf) {
                size_t noff = (kT < 3) ? (size_t)((kT + 1) * 32)
                                       : (size_t)(bb + 1) * (EDIM * EDIM) - (size_t)(3 * 32);
                // noff is relative to current (bb,kT=0) base; recompute absolutely:
                size_t abs_off = (kT < 3) ? ((size_t)bb * (EDIM * EDIM) + (size_t)(kT + 1) * 32)
                                          : ((size_t)(bb + 1) * (EDIM * EDIM));
                (void)noff;
                nr0 = *(const f32x4*)(Rp + abs_off);
                nr1 = *(const f32x4*)(Rp + abs_off + 4);
                nm0 = *(const f32x4*)(Mp + abs_off);
                nm1 = *(const f32x4*)(Mp + abs_off + 4);
            }

            // ---- convert current X to bf16 fragments ----
            bf16x8 ra, ma;
#pragma unroll
            for (int e = 0; e < 4; ++e) {
                ra[e]     = (__bf16)cr0[e];
                ra[4 + e] = (__bf16)cr1[e];
                ma[e]     = (__bf16)cm0[e];
                ma[4 + e] = (__bf16)cm1[e];
            }
            bf16x8 rn = neg8(ra);

            const int lbyte = (kT * 32 + s * 8) << 1;  // byte offset within 256B LDS row
#pragma unroll
            for (int nT = 0; nT < 8; ++nT) {
                int i   = (nT << 4) + li;
                int off = ((i << 8) + lbyte) ^ ((li & 7) << 4);
                bf16x8 pB = *(const bf16x8*)(smem + off);
                bf16x8 qB = *(const bf16x8*)(smem + 32768 + off);
                acc_re[nT] = __builtin_amdgcn_mfma_f32_16x16x32_bf16(ra, pB, acc_re[nT], 0, 0, 0);
                acc_re[nT] = __builtin_amdgcn_mfma_f32_16x16x32_bf16(ma, qB, acc_re[nT], 0, 0, 0);
                acc_im[nT] = __builtin_amdgcn_mfma_f32_16x16x32_bf16(ma, pB, acc_im[nT], 0, 0, 0);
                acc_im[nT] = __builtin_amdgcn_mfma_f32_16x16x32_bf16(rn, qB, acc_im[nT], 0, 0, 0);
            }

            cr0 = nr0; cr1 = nr1; cm0 = nm0; cm1 = nm1;
        }

        // ---- epilogue (Re only): weight by k[i,j] (f32 global), wave-reduce ----
        // D layout: col i = lane&15, row j = jrow0 + reg,  jrow0 = w*16 + s*4
        const int jrow0 = (w << 4) + (s << 2);
#pragma unroll
        for (int nT = 0; nT < 8; ++nT) {
            int i = (nT << 4) + li;
            const float* kp = Kern + (((size_t)i * EDIM + jrow0) << 1);  // 8 floats, 32B-aligned
            f32x4 k0 = *(const f32x4*)(kp);       // p0 q0 p1 q1
            f32x4 k1 = *(const f32x4*)(kp + 4);   // p2 q2 p3 q3
            float re = acc_re[nT][0] * k0[0] - acc_im[nT][0] * k0[1]
                     + acc_re[nT][1] * k0[2] - acc_im[nT][1] * k0[3]
                     + acc_re[nT][2] * k1[0] - acc_im[nT][2] * k1[1]
                     + acc_re[nT][3] * k1[2] - acc_im[nT][3] * k1[3];
            re += __shfl_xor(re, 16);
            re += __shfl_xor(re, 32);
            if (s == 0) part[w * EDIM + i] = re;
        }
        __syncthreads();   // partials visible

        if (t < EDIM) {
            float sum = part[t];
#pragma unroll
            for (int ww = 1; ww < 8; ++ww) sum += part[ww * EDIM + t];
            int oi = b * EDIM + t;
            if (oi < nout) out[oi] = sum;
        }
        __syncthreads();   // WAR: part reads done before next batch writes
    }
}

extern "C" void kernel_launch(void* const* d_in, const int* in_sizes, int n_in,
                              void* d_out, int out_size, void* d_ws, size_t ws_size,
                              hipStream_t stream) {
    const float* R    = (const float*)d_in[0];
    const float* M    = (const float*)d_in[1];
    const float* Kern = (const float*)d_in[2];
    float*       out  = (float*)d_out;
    const int    B    = in_sizes[0] / (EDIM * EDIM);   // 2048

    static int attr_done = 0;   // idempotent host-side attr (not a stream op)
    hipFuncSetAttribute((const void*)qmeas_kernel,
                        hipFuncAttributeMaxDynamicSharedMemorySize, LDS_BYTES);
    (void)attr_done;

    int grid = (B + NB - 1) / NB;   // 512
    qmeas_kernel<<<grid, 512, LDS_BYTES, stream>>>(R, M, Kern, out, B, out_size);
}

// Round 6
// 80.572 us; speedup vs baseline: 1.5933x; 1.5933x over previous
//
#include <hip/hip_runtime.h>
#include <hip/hip_bf16.h>
#include <stdint.h>

// out_re[b,i] = sum_j T_re[j,i]*p[i,j] - T_im[j,i]*q[i,j]   (d_out = Re only)
//   T_re = R*P^T + M*Q^T ; T_im = M*P^T - R*Q^T  via 16x16x32 bf16 MFMA.
// Round-6: revert to round-4 skeleton (2048 blocks, 1 batch/block, 64KB static
// LDS). Loop interchange: nT OUTER / kT INNER so live acc = 8 regs (was 64).
// X converted to bf16 fragments ra[4]/ma[4]/rn[4] once; 16 upfront f32x4 loads
// can all be in flight (fixes the VGPR-starved load serialization seen as
// VGPR_Count=64, all pipes <11% busy).

typedef __attribute__((ext_vector_type(8))) __bf16 bf16x8;
typedef __attribute__((ext_vector_type(4))) float f32x4;
typedef __attribute__((ext_vector_type(4))) unsigned int u32x4;

#define EDIM 128

static __device__ inline bf16x8 neg8(bf16x8 v) {
    u32x4 u = __builtin_bit_cast(u32x4, v);
    u ^= (u32x4){0x80008000u, 0x80008000u, 0x80008000u, 0x80008000u};
    return __builtin_bit_cast(bf16x8, u);
}

__global__ __launch_bounds__(512, 4) void qmeas_kernel(
    const float* __restrict__ R, const float* __restrict__ M,
    const float* __restrict__ Kern, float* __restrict__ out, int nout)
{
    __shared__ __align__(16) unsigned char smem[65536];

    const int t    = threadIdx.x;
    const int lane = t & 63;
    const int w    = t >> 6;       // wave 0..7
    const int li   = lane & 15;
    const int s    = lane >> 4;    // 0..3
    const int b    = blockIdx.x;

    // ---- stage kernel (f32 interleaved p,q -> bf16 Pb/Qb, XOR-swizzled) ----
    for (int it = 0; it < 4; ++it) {
        int idx = t + it * 512;            // 0..2047
        int i   = idx >> 4;                // row 0..127
        int l0  = (idx & 15) << 3;         // 0,8,...,120
        const float* g = Kern + (((size_t)i * EDIM + l0) << 1);
        f32x4 f0 = *(const f32x4*)(g);
        f32x4 f1 = *(const f32x4*)(g + 4);
        f32x4 f2 = *(const f32x4*)(g + 8);
        f32x4 f3 = *(const f32x4*)(g + 12);
        bf16x8 pv, qv;
        pv[0] = (__bf16)f0[0]; qv[0] = (__bf16)f0[1];
        pv[1] = (__bf16)f0[2]; qv[1] = (__bf16)f0[3];
        pv[2] = (__bf16)f1[0]; qv[2] = (__bf16)f1[1];
        pv[3] = (__bf16)f1[2]; qv[3] = (__bf16)f1[3];
        pv[4] = (__bf16)f2[0]; qv[4] = (__bf16)f2[1];
        pv[5] = (__bf16)f2[2]; qv[5] = (__bf16)f2[3];
        pv[6] = (__bf16)f3[0]; qv[6] = (__bf16)f3[1];
        pv[7] = (__bf16)f3[2]; qv[7] = (__bf16)f3[3];
        int off = (i * 256 + (l0 << 1)) ^ ((i & 7) << 4);
        *(bf16x8*)(smem + off)         = pv;   // Pb
        *(bf16x8*)(smem + 32768 + off) = qv;   // Qb
    }
    __syncthreads();

    // ---- load this wave's X rows (16 independent f32x4 loads, then cvt) ----
    const int    jj   = (w << 4) + li;            // this lane's A-row (j)
    const float* Rp   = R + (size_t)b * (EDIM * EDIM) + (size_t)jj * EDIM + s * 8;
    const float* Mp   = M + (size_t)b * (EDIM * EDIM) + (size_t)jj * EDIM + s * 8;

    f32x4 fr[8], fm[8];
#pragma unroll
    for (int u = 0; u < 4; ++u) {
        fr[2 * u]     = *(const f32x4*)(Rp + u * 32);
        fr[2 * u + 1] = *(const f32x4*)(Rp + u * 32 + 4);
        fm[2 * u]     = *(const f32x4*)(Mp + u * 32);
        fm[2 * u + 1] = *(const f32x4*)(Mp + u * 32 + 4);
    }
    bf16x8 ra[4], ma[4], rn[4];
#pragma unroll
    for (int u = 0; u < 4; ++u) {
#pragma unroll
        for (int e = 0; e < 4; ++e) {
            ra[u][e]     = (__bf16)fr[2 * u][e];
            ra[u][4 + e] = (__bf16)fr[2 * u + 1][e];
            ma[u][e]     = (__bf16)fm[2 * u][e];
            ma[u][4 + e] = (__bf16)fm[2 * u + 1][e];
        }
        rn[u] = neg8(ra[u]);
    }

    // ---- main: nT outer (live acc = are,aim = 8 regs), kT inner ----
    // D layout: col i = lane&15, row j = jrow0 + reg, jrow0 = w*16 + s*4
    const int jrow0 = (w << 4) + (s << 2);
    float re8[8];
#pragma unroll
    for (int nT = 0; nT < 8; ++nT) {
        const int i = (nT << 4) + li;
        const float* kp = Kern + (((size_t)i * EDIM + jrow0) << 1);
        f32x4 k0 = *(const f32x4*)(kp);       // p0 q0 p1 q1
        f32x4 k1 = *(const f32x4*)(kp + 4);   // p2 q2 p3 q3
        f32x4 are = (f32x4){0.f, 0.f, 0.f, 0.f};
        f32x4 aim = (f32x4){0.f, 0.f, 0.f, 0.f};
#pragma unroll
        for (int u = 0; u < 4; ++u) {
            int off = ((i << 8) + ((u * 32 + s * 8) << 1)) ^ ((li & 7) << 4);
            bf16x8 pB = *(const bf16x8*)(smem + off);
            bf16x8 qB = *(const bf16x8*)(smem + 32768 + off);
            are = __builtin_amdgcn_mfma_f32_16x16x32_bf16(ra[u], pB, are, 0, 0, 0);
            are = __builtin_amdgcn_mfma_f32_16x16x32_bf16(ma[u], qB, are, 0, 0, 0);
            aim = __builtin_amdgcn_mfma_f32_16x16x32_bf16(ma[u], pB, aim, 0, 0, 0);
            aim = __builtin_amdgcn_mfma_f32_16x16x32_bf16(rn[u], qB, aim, 0, 0, 0);
        }
        float re = are[0] * k0[0] - aim[0] * k0[1]
                 + are[1] * k0[2] - aim[1] * k0[3]
                 + are[2] * k1[0] - aim[2] * k1[1]
                 + are[3] * k1[2] - aim[3] * k1[3];
        re += __shfl_xor(re, 16);
        re += __shfl_xor(re, 32);
        re8[nT] = re;
    }

    // ---- all Pb/Qb reads done; reuse smem[0,4096) as f32 part[8][128] ----
    __syncthreads();
    float* part = (float*)smem;
    if (s == 0) {
#pragma unroll
        for (int nT = 0; nT < 8; ++nT) {
            part[w * EDIM + (nT << 4) + li] = re8[nT];
        }
    }
    __syncthreads();

    // ---- cross-wave reduce + store (Re only, guarded by nout) ----
    if (t < EDIM) {
        float sum = part[t];
#pragma unroll
        for (int ww = 1; ww < 8; ++ww) sum += part[ww * EDIM + t];
        int oi = b * EDIM + t;
        if (oi < nout) out[oi] = sum;
    }
}

extern "C" void kernel_launch(void* const* d_in, const int* in_sizes, int n_in,
                              void* d_out, int out_size, void* d_ws, size_t ws_size,
                              hipStream_t stream) {
    const float* R    = (const float*)d_in[0];
    const float* M    = (const float*)d_in[1];
    const float* Kern = (const float*)d_in[2];
    float*       out  = (float*)d_out;
    const int    B    = in_sizes[0] / (EDIM * EDIM);   // 2048
    qmeas_kernel<<<B, 512, 0, stream>>>(R, M, Kern, out, out_size);
}